// Round 2
// baseline (438.955 us; speedup 1.0000x reference)
//
#include <hip/hip_runtime.h>

// Local windowed 2D autocorrelation.
// x: [8, 64, 128, 128] fp32; out: [8, 64, 31, 31, 8, 8] fp32.
// KH=KW=8, SH=SW=4, no input padding.
//
// One thread per window, window in registers. Uses the autocorrelation
// symmetry corr(dy,dx) == corr(-dy,-dx): out[8-oy][8-ox] == out[oy][ox],
// so only 40 of the 64 offsets are computed (1368 MACs instead of 2304);
// rows 5..7 are reversed copies of rows 3..1 plus one edge (ox=0) value.
//
// __launch_bounds__(256,4) caps VGPRs at 128 (4 waves/SIMD); live set is
// ~85 regs (64 window + 8 acc). sched_barrier(0) between row sections stops
// the scheduler from interleaving rows and re-inflating register pressure
// (round 1: 256 VGPR + ~570 MB scratch spill traffic).

#define NH 31
#define NW 31
#define NWIN (8 * 64 * NH * NW)  // 492032

// Full row of 8 offsets for window-row shift DY: acc[ox] += corr(DY, ox-4).
template <int DY, int OX0, int OX1>
__device__ __forceinline__ void corr_row(const float (&win)[8][8], float* acc) {
#pragma unroll
  for (int i = 0; i < 8; ++i) {
    if (i + DY < 0 || i + DY >= 8) continue;  // compile-time after unroll
#pragma unroll
    for (int ox = OX0; ox < OX1; ++ox) {
#pragma unroll
      for (int j = 0; j < 8; ++j) {
        const int jj = j + ox - 4;
        if (jj < 0 || jj >= 8) continue;  // compile-time
        acc[ox - OX0] += win[i][j] * win[i + DY][jj];
      }
    }
  }
}

// Single edge value: corr(DY, dx=-4).
template <int DY>
__device__ __forceinline__ float corr_ox0(const float (&win)[8][8]) {
  float e = 0.f;
#pragma unroll
  for (int i = 0; i < 8; ++i) {
    if (i + DY < 0 || i + DY >= 8) continue;
#pragma unroll
    for (int j = 4; j < 8; ++j) e += win[i][j] * win[i + DY][j - 4];
  }
  return e;
}

__device__ __forceinline__ void store8(float* p, const float* a) {
  *reinterpret_cast<float4*>(p)     = make_float4(a[0], a[1], a[2], a[3]);
  *reinterpret_cast<float4*>(p + 4) = make_float4(a[4], a[5], a[6], a[7]);
}

__global__ __launch_bounds__(256, 4) void lacorr2d_kernel(
    const float* __restrict__ x, float* __restrict__ out) {
  int t = blockIdx.x * 256 + threadIdx.x;  // grid is exact: 492032 = 1922*256

  int w  = t % NW;
  int hw = t / NW;
  int h  = hw % NH;
  int bc = hw / NH;

  const float* src = x + (size_t)bc * (128 * 128) + (size_t)(h * 4) * 128 + (w * 4);

  float win[8][8];
#pragma unroll
  for (int r = 0; r < 8; ++r) {
    float4 a = *reinterpret_cast<const float4*>(src + r * 128);
    float4 b = *reinterpret_cast<const float4*>(src + r * 128 + 4);
    win[r][0] = a.x; win[r][1] = a.y; win[r][2] = a.z; win[r][3] = a.w;
    win[r][4] = b.x; win[r][5] = b.y; win[r][6] = b.z; win[r][7] = b.w;
  }

  float* dst = out + (size_t)t * 64;

  // --- row 0 (dy = -4): no in-range mirror, compute fully ---
  {
    float acc[8] = {0.f, 0.f, 0.f, 0.f, 0.f, 0.f, 0.f, 0.f};
    corr_row<-4, 0, 8>(win, acc);
    store8(dst, acc);
  }
  __builtin_amdgcn_sched_barrier(0);

  // --- pair (1,7): row 7 = [edge, reverse(acc[1..7])] ---
  {
    float acc[8] = {0.f, 0.f, 0.f, 0.f, 0.f, 0.f, 0.f, 0.f};
    corr_row<-3, 0, 8>(win, acc);
    store8(dst + 8, acc);
    float e = corr_ox0<3>(win);
    *reinterpret_cast<float4*>(dst + 56) = make_float4(e, acc[7], acc[6], acc[5]);
    *reinterpret_cast<float4*>(dst + 60) = make_float4(acc[4], acc[3], acc[2], acc[1]);
  }
  __builtin_amdgcn_sched_barrier(0);

  // --- pair (2,6) ---
  {
    float acc[8] = {0.f, 0.f, 0.f, 0.f, 0.f, 0.f, 0.f, 0.f};
    corr_row<-2, 0, 8>(win, acc);
    store8(dst + 16, acc);
    float e = corr_ox0<2>(win);
    *reinterpret_cast<float4*>(dst + 48) = make_float4(e, acc[7], acc[6], acc[5]);
    *reinterpret_cast<float4*>(dst + 52) = make_float4(acc[4], acc[3], acc[2], acc[1]);
  }
  __builtin_amdgcn_sched_barrier(0);

  // --- pair (3,5) ---
  {
    float acc[8] = {0.f, 0.f, 0.f, 0.f, 0.f, 0.f, 0.f, 0.f};
    corr_row<-1, 0, 8>(win, acc);
    store8(dst + 24, acc);
    float e = corr_ox0<1>(win);
    *reinterpret_cast<float4*>(dst + 40) = make_float4(e, acc[7], acc[6], acc[5]);
    *reinterpret_cast<float4*>(dst + 44) = make_float4(acc[4], acc[3], acc[2], acc[1]);
  }
  __builtin_amdgcn_sched_barrier(0);

  // --- row 4 (dy = 0): self-mirrored, compute ox 0..4, reflect 5..7 ---
  {
    float acc[5] = {0.f, 0.f, 0.f, 0.f, 0.f};
    corr_row<0, 0, 5>(win, acc);
    *reinterpret_cast<float4*>(dst + 32) = make_float4(acc[0], acc[1], acc[2], acc[3]);
    *reinterpret_cast<float4*>(dst + 36) = make_float4(acc[4], acc[3], acc[2], acc[1]);
  }
}

extern "C" void kernel_launch(void* const* d_in, const int* in_sizes, int n_in,
                              void* d_out, int out_size, void* d_ws, size_t ws_size,
                              hipStream_t stream) {
  const float* x = (const float*)d_in[0];
  float* out = (float*)d_out;
  int grid = (NWIN + 255) / 256;
  lacorr2d_kernel<<<grid, 256, 0, stream>>>(x, out);
}

// Round 3
// 219.649 us; speedup vs baseline: 1.9984x; 1.9984x over previous
//
#include <hip/hip_runtime.h>

// Local windowed 2D autocorrelation.
// x: [8, 64, 128, 128] fp32; out: [8, 64, 31, 31, 8, 8] fp32.
// KH=KW=8, SH=SW=4, no input padding.
//
// Decomposition: one thread per (window, oy). Each thread computes one
// 8-value output row: out[win][oy][ox] = sum_{i,j} W[i][j]*W[i+dy][j+dx],
// dy=oy-4, dx=ox-4, OOB-of-window treated as zero.
//
// Register discipline (lesson from rounds 1-2, which spilled at 256 and 64
// VGPR respectively with the whole 8x8 window live): per i-iteration only
// TWO 8-float rows are live, re-loaded from global (L1/L2-served; input is
// 33.5 MB, L2-resident). All locals are compile-time indexed -> registers.

#define NH 31
#define NW 31
#define NWIN (8 * 64 * NH * NW)      // 492032 windows
#define NTHREADS (NWIN * 8)          // 3936256 = 15376 * 256

__global__ __launch_bounds__(256) void lacorr2d_kernel(
    const float* __restrict__ x, float* __restrict__ out) {
  int t = blockIdx.x * 256 + threadIdx.x;  // grid exact

  int oy  = t & 7;
  int win = t >> 3;
  int w   = win % NW;
  int hw  = win / NW;
  int h   = hw % NH;
  int bc  = hw / NH;

  const float* src = x + (size_t)bc * (128 * 128) + (size_t)(h * 4) * 128 + (w * 4);
  const int dy = oy - 4;

  float acc[8] = {0.f, 0.f, 0.f, 0.f, 0.f, 0.f, 0.f, 0.f};

#pragma unroll
  for (int i = 0; i < 8; ++i) {
    const int i2 = i + dy;
    if ((unsigned)i2 < 8u) {  // per-lane exec mask; loads+FMAs predicated
      const float* pa = src + i * 128;
      const float* pb = src + i2 * 128;
      float4 a0 = *reinterpret_cast<const float4*>(pa);
      float4 a1 = *reinterpret_cast<const float4*>(pa + 4);
      float4 b0 = *reinterpret_cast<const float4*>(pb);
      float4 b1 = *reinterpret_cast<const float4*>(pb + 4);
      float ra[8] = {a0.x, a0.y, a0.z, a0.w, a1.x, a1.y, a1.z, a1.w};
      float rb[8] = {b0.x, b0.y, b0.z, b0.w, b1.x, b1.y, b1.z, b1.w};
#pragma unroll
      for (int ox = 0; ox < 8; ++ox) {
        const int dx = ox - 4;
#pragma unroll
        for (int j = 0; j < 8; ++j) {
          const int jj = j + dx;
          if (jj < 0 || jj >= 8) continue;  // compile-time after unroll
          acc[ox] += ra[j] * rb[jj];
        }
      }
    }
  }

  float* dst = out + (size_t)win * 64 + oy * 8;
  *reinterpret_cast<float4*>(dst)     = make_float4(acc[0], acc[1], acc[2], acc[3]);
  *reinterpret_cast<float4*>(dst + 4) = make_float4(acc[4], acc[5], acc[6], acc[7]);
}

extern "C" void kernel_launch(void* const* d_in, const int* in_sizes, int n_in,
                              void* d_out, int out_size, void* d_ws, size_t ws_size,
                              hipStream_t stream) {
  const float* x = (const float*)d_in[0];
  float* out = (float*)d_out;
  int grid = NTHREADS / 256;
  lacorr2d_kernel<<<grid, 256, 0, stream>>>(x, out);
}